// Round 21
// baseline (226.407 us; speedup 1.0000x reference)
//
#include <hip/hip_runtime.h>
#include <hip/hip_fp16.h>
#include <stdint.h>
#include <math.h>

#define KB 512
#define KT 2048
#define KS 16
#define KPD 4
#define QT 512          // timesteps per quarter
#define NQ (KT / QT)
#define QSTR 515        // row stride (elements) for QR/zs (odd; capacity 512)
#define HSTR 40         // f16 per H-slice row

typedef _Float16 f16;
typedef _Float16 f16x8 __attribute__((ext_vector_type(8)));
typedef float f32x4 __attribute__((ext_vector_type(4)));

#define MFMA16(A, B, C) __builtin_amdgcn_mfma_f32_16x16x32_f16(A, B, C, 0, 0, 0)

__device__ __forceinline__ float softplus_f(float x) {
    float ax = fabsf(x);
    float e  = __expf(-ax);
    return fmaxf(x, 0.0f) + __logf(1.0f + e);
}
__device__ __forceinline__ float sigmoid_f(float x) {
    return __builtin_amdgcn_rcpf(1.0f + __expf(-x));
}
__device__ __forceinline__ float h2f_lo(uint32_t w) {
    return __half2float(__ushort_as_half((unsigned short)(w & 0xffffu)));
}
__device__ __forceinline__ float h2f_hi(uint32_t w) {
    return __half2float(__ushort_as_half((unsigned short)(w >> 16)));
}
__device__ __forceinline__ f16x8 zero8() {
    f16x8 v;
#pragma unroll
    for (int i = 0; i < 8; ++i) v[i] = (f16)0;
    return v;
}
__device__ __forceinline__ int spos(int t) { return t ^ ((t >> 5) & 31); }

__device__ __forceinline__ uint32_t pkrelu(float a, float b) {
    auto h = __builtin_amdgcn_cvt_pkrtz(fmaxf(a, 0.f), fmaxf(b, 0.f));
    uint32_t w; __builtin_memcpy(&w, &h, 4);
    return w;
}
__device__ __forceinline__ uint16_t f2h(float x) {
    return (uint16_t)__half_as_ushort(__float2half_rn(x));
}
__device__ __forceinline__ float h2f(uint16_t x) {
    return __half2float(__ushort_as_half((unsigned short)x));
}

struct HalfMem {
    uint32_t* QRl;   // [16][QSTR]
    float*    Gl;    // [512]
    uint16_t* Hs;    // [8][16][HSTR] per-wave H slices
    uint16_t* zsh;   // [16][QSTR] f16 z/mu
};

// ================== shared per-half body (R20-verified) ==================
__device__ __forceinline__ void kalman_half(
    HalfMem M, int b, int lh,
    const float* __restrict__ z, const float* __restrict__ p,
    const float* __restrict__ mu0, const float* __restrict__ P0,
    const float* __restrict__ Wq1, const float* __restrict__ bq1,
    const float* __restrict__ Wq2, const float* __restrict__ bq2,
    const float* __restrict__ Wr1, const float* __restrict__ br1,
    const float* __restrict__ Wr2, const float* __restrict__ br2,
    const float* __restrict__ Wg1, const float* __restrict__ bg1,
    const float* __restrict__ Wg2, const float* __restrict__ bg2,
    float* __restrict__ out)
{
    const int wv = lh >> 6;          // 0..7 within half
    const int l = lh & 63;
    const int g = l >> 4;
    const int c = l & 15;

    uint32_t* __restrict__ QRl = M.QRl;
    float* __restrict__ Gl = M.Gl;
    uint16_t* __restrict__ zsh = M.zsh;
    f16* __restrict__ Hw = reinterpret_cast<f16*>(M.Hs) + wv * (KS * HSTR);

    const float* __restrict__ zb = z + (size_t)b * KT * KS;
    const float* __restrict__ pb = p + (size_t)b * KT * KPD;
    float* __restrict__ ob = out + (size_t)b * KT * KS;

    // ---- const A-frags: W1cat^T ----
    f16x8 fA1[10];
#pragma unroll
    for (int m = 0; m < 10; ++m) {
        const float* W = (m < 4) ? (Wq1 + m * 16)
                       : (m < 8) ? (Wr1 + (m - 4) * 16)
                                 : (Wg1 + (m - 8) * 16);
        const int ld = (m < 8) ? 64 : 32;
        float w0 = W[0 * ld + c], w1 = W[1 * ld + c],
              w2 = W[2 * ld + c], w3 = W[3 * ld + c];
        f16x8 a = zero8();
        if (g == 0) { a[0] = (f16)w0; a[1] = (f16)w1; a[2] = (f16)w2; a[3] = (f16)w3; }
        fA1[m] = a;
    }
    // ---- const A-frags: W2cat^T ----
    f16x8 fA2[5];
#pragma unroll
    for (int i = 0; i < 4; ++i) {
        const float* W = (i < 2) ? Wq2 : Wr2;
        const int kb = (i & 1) * 32;
        f16x8 a;
#pragma unroll
        for (int j = 0; j < 8; ++j) a[j] = (f16)W[(kb + g * 8 + j) * 16 + c];
        fA2[i] = a;
    }
    {
        f16x8 a = zero8();
        if (c == 0) {
#pragma unroll
            for (int j = 0; j < 8; ++j) a[j] = (f16)Wg2[g * 8 + j];
        }
        fA2[4] = a;
    }
    const float bQ0 = bq2[g * 4 + 0], bQ1 = bq2[g * 4 + 1],
                bQ2 = bq2[g * 4 + 2], bQ3 = bq2[g * 4 + 3];
    const float bR0 = br2[g * 4 + 0], bR1 = br2[g * 4 + 1],
                bR2 = br2[g * 4 + 2], bR3 = br2[g * 4 + 3];
    const float bG = bg2[0];

    float muA = mu0[b * KS + wv],     PA = P0[b * KS + wv];
    float muB = mu0[b * KS + wv + 8], PB = P0[b * KS + wv + 8];

    auto scan_s = [&](int s, float& mu_q, float& P_q) {
        uint32_t qr[8];
        const uint32_t* qrow = QRl + (size_t)s * QSTR;
        float zvv[8], gvv[8];
#pragma unroll
        for (int i = 0; i < 8; ++i) {
            const int ps = spos(l * 8 + i);
            qr[i] = qrow[ps];
            zvv[i] = h2f(zsh[s * QSTR + ps]);
            gvv[i] = Gl[ps];
        }
        float c00 = 1.f, c01 = 0.f, c10 = 0.f, c11 = 1.f;
#pragma unroll
        for (int i = 0; i < 8; ++i) {
            float Q = h2f_lo(qr[i]), Rr = h2f_hi(qr[i]);
            float ta = fmaf(Q, c10, c00);
            float tb = fmaf(Q, c11, c01);
            float n10 = fmaf(Q + Rr, c10, c00);
            float n11 = fmaf(Q + Rr, c11, c01);
            c00 = Rr * ta; c01 = Rr * tb; c10 = n10; c11 = n11;
        }
        float rn = __builtin_amdgcn_rcpf(c11);
        float ma = c00 * rn, mb = c01 * rn, mc = c10 * rn;
#pragma unroll
        for (int r = 0; r < 6; ++r) {
            const int d = 1 << r;
            float pa = __shfl_up(ma, d);
            float pbv = __shfl_up(mb, d);
            float pc = __shfl_up(mc, d);
            float na = fmaf(ma, pa, mb * pc);
            float nb = fmaf(ma, pbv, mb);
            float nc = fmaf(mc, pa, pc);
            float nd = fmaf(mc, pbv, 1.f);
            float rr = __builtin_amdgcn_rcpf(nd);
            bool act = (l >= d);
            ma = act ? na * rr : ma;
            mb = act ? nb * rr : mb;
            mc = act ? nc * rr : mc;
        }
        float ea = __shfl_up(ma, 1);
        float eb = __shfl_up(mb, 1);
        float ec = __shfl_up(mc, 1);
        if (l == 0) { ea = 1.f; eb = 0.f; ec = 0.f; }
        float P = fmaf(ea, P_q, eb) * __builtin_amdgcn_rcpf(fmaf(ec, P_q, 1.f));

        float av[8], bw[8];
        float A = 1.f, Bv = 0.f;
#pragma unroll
        for (int i = 0; i < 8; ++i) {
            float Q = h2f_lo(qr[i]), Rr = h2f_hi(qr[i]);
            float Pp = P + Q;
            float K0 = Pp * __builtin_amdgcn_rcpf(Pp + Rr);
            float Kk = __builtin_amdgcn_fmed3f(K0, 1e-6f, 0.95f);
            float gk = gvv[i] * Kk;
            av[i] = 1.f - gk;
            bw[i] = gk * zvv[i];
            P = fmaf(-Kk, Pp, Pp);
            A = A * av[i];
            Bv = fmaf(av[i], Bv, bw[i]);
        }
        float P_end = __shfl(P, 63);
#pragma unroll
        for (int r = 0; r < 6; ++r) {
            const int d = 1 << r;
            float pA = __shfl_up(A, d);
            float pB = __shfl_up(Bv, d);
            float nA = A * pA;
            float nB = fmaf(A, pB, Bv);
            bool act = (l >= d);
            A  = act ? nA : A;
            Bv = act ? nB : Bv;
        }
        float eA = __shfl_up(A, 1);
        float eB = __shfl_up(Bv, 1);
        if (l == 0) { eA = 1.f; eB = 0.f; }
        float mu = fmaf(eA, mu_q, eB);
#pragma unroll
        for (int i = 0; i < 8; ++i) {
            mu = fmaf(av[i], mu, bw[i]);
            zsh[s * QSTR + spos(l * 8 + i)] = f2h(mu);
        }
        mu_q = __shfl(mu, 63);
        P_q = P_end;
    };

    for (int q = 0; q < NQ; ++q) {
        // ===== phase A+B: MLP (small-slice H) + z staging =====
        {
            const int trow = q * QT + wv * 64;
            const float4 pv = *reinterpret_cast<const float4*>(pb + (size_t)(trow + l) * KPD);

#pragma unroll
            for (int n = 0; n < 4; ++n) {
                f16x8 fBP;
                {
                    const int src = n * 16 + c;
                    float x = __shfl(pv.x, src);
                    float y = __shfl(pv.y, src);
                    float zz = __shfl(pv.z, src);
                    float w = __shfl(pv.w, src);
                    fBP = zero8();
                    if (g == 0) { fBP[0] = (f16)x; fBP[1] = (f16)y; fBP[2] = (f16)zz; fBP[3] = (f16)w; }
                }

                f32x4 aq; aq[0] = bQ0; aq[1] = bQ1; aq[2] = bQ2; aq[3] = bQ3;
                f32x4 ar; ar[0] = bR0; ar[1] = bR1; ar[2] = bR2; ar[3] = bR3;
                f32x4 ag; ag[0] = 0.f; ag[1] = 0.f; ag[2] = 0.f; ag[3] = 0.f;

                uint32_t* Hd = reinterpret_cast<uint32_t*>(Hw);   // dword view, stride 20

#pragma unroll
                for (int X = 0; X < 5; ++X) {
                    const int m0 = 2 * X, m1 = 2 * X + 1;
                    {
                        const float* bs = (m0 < 4) ? (bq1 + m0 * 16)
                                        : (m0 < 8) ? (br1 + (m0 - 4) * 16)
                                                   : (bg1 + (m0 - 8) * 16);
                        f32x4 acc;
                        acc[0] = bs[g * 4 + 0]; acc[1] = bs[g * 4 + 1];
                        acc[2] = bs[g * 4 + 2]; acc[3] = bs[g * 4 + 3];
                        acc = MFMA16(fA1[m0], fBP, acc);
                        Hd[c * 20 + g * 2 + 0] = pkrelu(acc[0], acc[1]);
                        Hd[c * 20 + g * 2 + 1] = pkrelu(acc[2], acc[3]);
                    }
                    {
                        const float* bs = (m1 < 4) ? (bq1 + m1 * 16)
                                        : (m1 < 8) ? (br1 + (m1 - 4) * 16)
                                                   : (bg1 + (m1 - 8) * 16);
                        f32x4 acc;
                        acc[0] = bs[g * 4 + 0]; acc[1] = bs[g * 4 + 1];
                        acc[2] = bs[g * 4 + 2]; acc[3] = bs[g * 4 + 3];
                        acc = MFMA16(fA1[m1], fBP, acc);
                        Hd[c * 20 + 8 + g * 2 + 0] = pkrelu(acc[0], acc[1]);
                        Hd[c * 20 + 8 + g * 2 + 1] = pkrelu(acc[2], acc[3]);
                    }
                    f16x8 fb = *reinterpret_cast<const f16x8*>(Hw + c * HSTR + g * 8);
                    if (X == 0)      aq = MFMA16(fA2[0], fb, aq);
                    else if (X == 1) aq = MFMA16(fA2[1], fb, aq);
                    else if (X == 2) ar = MFMA16(fA2[2], fb, ar);
                    else if (X == 3) ar = MFMA16(fA2[3], fb, ar);
                    else             ag = MFMA16(fA2[4], fb, ag);
                }

                const int tt = wv * 64 + n * 16 + c;
                const int ps = spos(tt);
#pragma unroll
                for (int i = 0; i < 4; ++i) {
                    float Qv = softplus_f(aq[i]) + 1e-8f;
                    float Rv = softplus_f(ar[i]) + 1e-8f;
                    auto pk = __builtin_amdgcn_cvt_pkrtz(Qv, Rv);
                    uint32_t w; __builtin_memcpy(&w, &pk, 4);
                    QRl[(size_t)(g * 4 + i) * QSTR + ps] = w;
                }
                if (g == 0)
                    Gl[ps] = sigmoid_f(ag[0] + bG);
            }

            // z staging
            const float4* zq = reinterpret_cast<const float4*>(zb + (size_t)q * QT * KS);
#pragma unroll
            for (int v = 0; v < 4; ++v) {
                int k = lh + 512 * v;
                float4 w = zq[k];
                int t = k >> 2, s0 = (k & 3) << 2;
                const int ps = spos(t);
                zsh[(s0 + 0) * QSTR + ps] = f2h(w.x);
                zsh[(s0 + 1) * QSTR + ps] = f2h(w.y);
                zsh[(s0 + 2) * QSTR + ps] = f2h(w.z);
                zsh[(s0 + 3) * QSTR + ps] = f2h(w.w);
            }
        }
        __syncthreads();

        // ===== phase C: scans =====
        scan_s(wv, muA, PA);
        scan_s(wv + 8, muB, PB);
        __syncthreads();

        // ===== phase D: out =====
        {
            float* od = ob + (size_t)q * QT * KS;
#pragma unroll
            for (int v = 0; v < 4; ++v) {
                int k = lh + 512 * v;
                int t = k >> 2, s0 = (k & 3) << 2;
                const int ps = spos(t);
                float4 w;
                w.x = h2f(zsh[(s0 + 0) * QSTR + ps]);
                w.y = h2f(zsh[(s0 + 1) * QSTR + ps]);
                w.z = h2f(zsh[(s0 + 2) * QSTR + ps]);
                w.w = h2f(zsh[(s0 + 3) * QSTR + ps]);
                *reinterpret_cast<float4*>(od + 4 * (size_t)k) = w;
            }
        }
        __syncthreads();
    }
}

// ================== kernel A: 2 b per 1024-thread block (one block/CU) ==================
__global__ __launch_bounds__(1024)
__attribute__((amdgpu_waves_per_eu(2, 4)))
void kalman_two(
    const float* __restrict__ z, const float* __restrict__ p,
    const float* __restrict__ mu0, const float* __restrict__ P0,
    const float* __restrict__ Wq1, const float* __restrict__ bq1,
    const float* __restrict__ Wq2, const float* __restrict__ bq2,
    const float* __restrict__ Wr1, const float* __restrict__ br1,
    const float* __restrict__ Wr2, const float* __restrict__ br2,
    const float* __restrict__ Wg1, const float* __restrict__ bg1,
    const float* __restrict__ Wg2, const float* __restrict__ bg2,
    float* __restrict__ out)
{
    __shared__ __align__(16) uint32_t QRl2[2][KS * QSTR];
    __shared__ __align__(16) float    Gl2[2][QT];
    __shared__ __align__(16) uint16_t Hs2[2][8 * KS * HSTR];
    __shared__ __align__(16) uint16_t zsh2[2][KS * QSTR];

    const int tid = threadIdx.x;
    const int h = tid >> 9;
    const int lh = tid & 511;
    const int b = blockIdx.x * 2 + h;

    HalfMem M;
    M.QRl = QRl2[h];
    M.Gl  = Gl2[h];
    M.Hs  = Hs2[h];
    M.zsh = zsh2[h];

    kalman_half(M, b, lh, z, p, mu0, P0,
                Wq1, bq1, Wq2, bq2, Wr1, br1, Wr2, br2,
                Wg1, bg1, Wg2, bg2, out);
}

// ================== kernel B: fallback — R20-proven 512-thread kernel ==================
__global__ __launch_bounds__(512, 2) void kalman_one(
    const float* __restrict__ z, const float* __restrict__ p,
    const float* __restrict__ mu0, const float* __restrict__ P0,
    const float* __restrict__ Wq1, const float* __restrict__ bq1,
    const float* __restrict__ Wq2, const float* __restrict__ bq2,
    const float* __restrict__ Wr1, const float* __restrict__ br1,
    const float* __restrict__ Wr2, const float* __restrict__ br2,
    const float* __restrict__ Wg1, const float* __restrict__ bg1,
    const float* __restrict__ Wg2, const float* __restrict__ bg2,
    float* __restrict__ out)
{
    __shared__ __align__(16) uint32_t QRl1[KS * QSTR];
    __shared__ __align__(16) float    Gl1[QT];
    __shared__ __align__(16) uint16_t Hs1[8 * KS * HSTR];
    __shared__ __align__(16) uint16_t zsh1[KS * QSTR];

    HalfMem M;
    M.QRl = QRl1;
    M.Gl  = Gl1;
    M.Hs  = Hs1;
    M.zsh = zsh1;

    kalman_half(M, blockIdx.x, threadIdx.x, z, p, mu0, P0,
                Wq1, bq1, Wq2, bq2, Wr1, br1, Wr2, br2,
                Wg1, bg1, Wg2, bg2, out);
}

// ---------------- launcher ----------------
extern "C" void kernel_launch(void* const* d_in, const int* in_sizes, int n_in,
                              void* d_out, int out_size, void* d_ws, size_t ws_size,
                              hipStream_t stream) {
    const float* z   = (const float*)d_in[0];
    const float* p   = (const float*)d_in[1];
    const float* mu0 = (const float*)d_in[2];
    const float* P0  = (const float*)d_in[3];
    const float* Wq1 = (const float*)d_in[4];
    const float* bq1 = (const float*)d_in[5];
    const float* Wq2 = (const float*)d_in[6];
    const float* bq2 = (const float*)d_in[7];
    const float* Wr1 = (const float*)d_in[8];
    const float* br1 = (const float*)d_in[9];
    const float* Wr2 = (const float*)d_in[10];
    const float* br2 = (const float*)d_in[11];
    const float* Wg1 = (const float*)d_in[12];
    const float* bg1 = (const float*)d_in[13];
    const float* Wg2 = (const float*)d_in[14];
    const float* bg2 = (const float*)d_in[15];
    float* out = (float*)d_out;

    // Host-side attribute query (graph-safe, deterministic): detect VGPR squeeze.
    hipFuncAttributes attr{};
    bool use_two = false;
    if (hipFuncGetAttributes(&attr, (const void*)kalman_two) == hipSuccess)
        use_two = (attr.numRegs >= 96);   // spill signature is numRegs~64

    if (use_two) {
        hipLaunchKernelGGL(kalman_two, dim3(KB / 2), dim3(1024), 0, stream,
                           z, p, mu0, P0, Wq1, bq1, Wq2, bq2,
                           Wr1, br1, Wr2, br2, Wg1, bg1, Wg2, bg2, out);
    } else {
        hipLaunchKernelGGL(kalman_one, dim3(KB), dim3(512), 0, stream,
                           z, p, mu0, P0, Wq1, bq1, Wq2, bq2,
                           Wr1, br1, Wr2, br2, Wg1, bg1, Wg2, bg2, out);
    }
}

// Round 22
// 86.495 us; speedup vs baseline: 2.6176x; 2.6176x over previous
//
#include <hip/hip_runtime.h>
#include <hip/hip_fp16.h>
#include <stdint.h>
#include <math.h>

#define KB 512
#define KT 2048
#define KS 16
#define KPD 4
#define QT 512          // timesteps per quarter
#define NQ (KT / QT)
#define QSTR 515        // row stride (elements) for QR/zs (odd; capacity 512)
#define HSTR 40         // f16 per H-slice row

typedef _Float16 f16;
typedef _Float16 f16x8 __attribute__((ext_vector_type(8)));
typedef float f32x4 __attribute__((ext_vector_type(4)));

#define MFMA16(A, B, C) __builtin_amdgcn_mfma_f32_16x16x32_f16(A, B, C, 0, 0, 0)

__device__ __forceinline__ float softplus_f(float x) {
    float ax = fabsf(x);
    float e  = __expf(-ax);
    return fmaxf(x, 0.0f) + __logf(1.0f + e);
}
__device__ __forceinline__ float sigmoid_f(float x) {
    return __builtin_amdgcn_rcpf(1.0f + __expf(-x));
}
__device__ __forceinline__ float h2f_lo(uint32_t w) {
    return __half2float(__ushort_as_half((unsigned short)(w & 0xffffu)));
}
__device__ __forceinline__ float h2f_hi(uint32_t w) {
    return __half2float(__ushort_as_half((unsigned short)(w >> 16)));
}
__device__ __forceinline__ f16x8 zero8() {
    f16x8 v;
#pragma unroll
    for (int i = 0; i < 8; ++i) v[i] = (f16)0;
    return v;
}
__device__ __forceinline__ int spos(int t) { return t ^ ((t >> 5) & 31); }

__device__ __forceinline__ uint32_t pkrelu(float a, float b) {
    auto h = __builtin_amdgcn_cvt_pkrtz(fmaxf(a, 0.f), fmaxf(b, 0.f));
    uint32_t w; __builtin_memcpy(&w, &h, 4);
    return w;
}
__device__ __forceinline__ uint16_t f2h(float x) {
    return (uint16_t)__half_as_ushort(__float2half_rn(x));
}
__device__ __forceinline__ float h2f(uint16_t x) {
    return __half2float(__ushort_as_half((unsigned short)x));
}

// =====================================================================
// kernel A: slim-register variant — weights live in LDS, target VGPR<=64
// =====================================================================
__global__ __launch_bounds__(512, 4) void kalman_fast(
    const float* __restrict__ z, const float* __restrict__ p,
    const float* __restrict__ mu0, const float* __restrict__ P0,
    const float* __restrict__ Wq1, const float* __restrict__ bq1,
    const float* __restrict__ Wq2, const float* __restrict__ bq2,
    const float* __restrict__ Wr1, const float* __restrict__ br1,
    const float* __restrict__ Wr2, const float* __restrict__ br2,
    const float* __restrict__ Wg1, const float* __restrict__ bg1,
    const float* __restrict__ Wg2, const float* __restrict__ bg2,
    float* __restrict__ out)
{
    __shared__ __align__(16) uint32_t QRl[KS * QSTR];     // 32,960 B [s][spos(t)]
    __shared__ __align__(16) float    Gl[QT];             //  2,048 B [spos(t)]
    __shared__ __align__(16) uint16_t Hs[8 * KS * HSTR];  // 10,240 B per-wave H slices
    __shared__ __align__(16) uint16_t zsh[KS * QSTR];     // 16,480 B f16 z/mu
    __shared__ __align__(16) uint32_t WA1[10 * 16 * 2];   //  1,280 B fA1 payload [m][c] u2
    __shared__ __align__(16) uint32_t WA2[5 * 64 * 4];    //  5,120 B fA2 frags [i][l] u4

    const int tid = threadIdx.x;
    const int wv = tid >> 6;
    const int l = tid & 63;
    const int g = l >> 4;
    const int c = l & 15;
    const int b = blockIdx.x;

    f16* __restrict__ Hw = reinterpret_cast<f16*>(Hs) + wv * (KS * HSTR);

    const float* __restrict__ zb = z + (size_t)b * KT * KS;
    const float* __restrict__ pb = p + (size_t)b * KT * KPD;
    float* __restrict__ ob = out + (size_t)b * KT * KS;

    // ---- stage weight fragments into LDS (once) ----
    if (tid < 160) {
        const int m = tid >> 4, cc = tid & 15;
        const float* W = (m < 4) ? (Wq1 + m * 16)
                       : (m < 8) ? (Wr1 + (m - 4) * 16)
                                 : (Wg1 + (m - 8) * 16);
        const int ld = (m < 8) ? 64 : 32;
        f16 v[4];
        v[0] = (f16)W[0 * ld + cc]; v[1] = (f16)W[1 * ld + cc];
        v[2] = (f16)W[2 * ld + cc]; v[3] = (f16)W[3 * ld + cc];
        uint32_t w0, w1;
        __builtin_memcpy(&w0, &v[0], 4);
        __builtin_memcpy(&w1, &v[2], 4);
        WA1[(m * 16 + cc) * 2 + 0] = w0;
        WA1[(m * 16 + cc) * 2 + 1] = w1;
    }
    if (tid < 320) {
        const int i = tid >> 6, ll = tid & 63;
        const int gg = ll >> 4, cc = ll & 15;
        f16x8 a = zero8();
        if (i < 4) {
            const float* W = (i < 2) ? Wq2 : Wr2;
            const int kb = (i & 1) * 32;
#pragma unroll
            for (int j = 0; j < 8; ++j) a[j] = (f16)W[(kb + gg * 8 + j) * 16 + cc];
        } else if (cc == 0) {
#pragma unroll
            for (int j = 0; j < 8; ++j) a[j] = (f16)Wg2[gg * 8 + j];
        }
        uint4 t;
        __builtin_memcpy(&t, &a, 16);
        *reinterpret_cast<uint4*>(&WA2[(i * 64 + ll) * 4]) = t;
    }

    const float bQ0 = bq2[g * 4 + 0], bQ1 = bq2[g * 4 + 1],
                bQ2 = bq2[g * 4 + 2], bQ3 = bq2[g * 4 + 3];
    const float bR0 = br2[g * 4 + 0], bR1 = br2[g * 4 + 1],
                bR2 = br2[g * 4 + 2], bR3 = br2[g * 4 + 3];
    const float bG = bg2[0];

    float muA = mu0[b * KS + wv],     PA = P0[b * KS + wv];
    float muB = mu0[b * KS + wv + 8], PB = P0[b * KS + wv + 8];

    __syncthreads();   // weights staged

    auto scan_s = [&](int s, float& mu_q, float& P_q) {
        uint32_t qr[8];
        const uint32_t* qrow = QRl + (size_t)s * QSTR;
        float zvv[8], gvv[8];
#pragma unroll
        for (int i = 0; i < 8; ++i) {
            const int ps = spos(l * 8 + i);
            qr[i] = qrow[ps];
            zvv[i] = h2f(zsh[s * QSTR + ps]);
            gvv[i] = Gl[ps];
        }
        float c00 = 1.f, c01 = 0.f, c10 = 0.f, c11 = 1.f;
#pragma unroll
        for (int i = 0; i < 8; ++i) {
            float Q = h2f_lo(qr[i]), Rr = h2f_hi(qr[i]);
            float ta = fmaf(Q, c10, c00);
            float tb = fmaf(Q, c11, c01);
            float n10 = fmaf(Q + Rr, c10, c00);
            float n11 = fmaf(Q + Rr, c11, c01);
            c00 = Rr * ta; c01 = Rr * tb; c10 = n10; c11 = n11;
        }
        float rn = __builtin_amdgcn_rcpf(c11);
        float ma = c00 * rn, mb = c01 * rn, mc = c10 * rn;
#pragma unroll
        for (int r = 0; r < 6; ++r) {
            const int d = 1 << r;
            float pa = __shfl_up(ma, d);
            float pbv = __shfl_up(mb, d);
            float pc = __shfl_up(mc, d);
            float na = fmaf(ma, pa, mb * pc);
            float nb = fmaf(ma, pbv, mb);
            float nc = fmaf(mc, pa, pc);
            float nd = fmaf(mc, pbv, 1.f);
            float rr = __builtin_amdgcn_rcpf(nd);
            bool act = (l >= d);
            ma = act ? na * rr : ma;
            mb = act ? nb * rr : mb;
            mc = act ? nc * rr : mc;
        }
        float ea = __shfl_up(ma, 1);
        float eb = __shfl_up(mb, 1);
        float ec = __shfl_up(mc, 1);
        if (l == 0) { ea = 1.f; eb = 0.f; ec = 0.f; }
        float P = fmaf(ea, P_q, eb) * __builtin_amdgcn_rcpf(fmaf(ec, P_q, 1.f));

        float av[8], bw[8];
        float A = 1.f, Bv = 0.f;
#pragma unroll
        for (int i = 0; i < 8; ++i) {
            float Q = h2f_lo(qr[i]), Rr = h2f_hi(qr[i]);
            float Pp = P + Q;
            float K0 = Pp * __builtin_amdgcn_rcpf(Pp + Rr);
            float Kk = __builtin_amdgcn_fmed3f(K0, 1e-6f, 0.95f);
            float gk = gvv[i] * Kk;
            av[i] = 1.f - gk;
            bw[i] = gk * zvv[i];
            P = fmaf(-Kk, Pp, Pp);
            A = A * av[i];
            Bv = fmaf(av[i], Bv, bw[i]);
        }
        float P_end = __shfl(P, 63);
#pragma unroll
        for (int r = 0; r < 6; ++r) {
            const int d = 1 << r;
            float pA = __shfl_up(A, d);
            float pB = __shfl_up(Bv, d);
            float nA = A * pA;
            float nB = fmaf(A, pB, Bv);
            bool act = (l >= d);
            A  = act ? nA : A;
            Bv = act ? nB : Bv;
        }
        float eA = __shfl_up(A, 1);
        float eB = __shfl_up(Bv, 1);
        if (l == 0) { eA = 1.f; eB = 0.f; }
        float mu = fmaf(eA, mu_q, eB);
#pragma unroll
        for (int i = 0; i < 8; ++i) {
            mu = fmaf(av[i], mu, bw[i]);
            zsh[s * QSTR + spos(l * 8 + i)] = f2h(mu);
        }
        mu_q = __shfl(mu, 63);
        P_q = P_end;
    };

    for (int q = 0; q < NQ; ++q) {
        // ===== phase A+B: MLP (weights from LDS) + z staging =====
        {
            const int trow = q * QT + wv * 64;
            const float4 pv = *reinterpret_cast<const float4*>(pb + (size_t)(trow + l) * KPD);

#pragma unroll
            for (int n = 0; n < 4; ++n) {
                f16x8 fBP;
                {
                    const int src = n * 16 + c;
                    float x = __shfl(pv.x, src);
                    float y = __shfl(pv.y, src);
                    float zz = __shfl(pv.z, src);
                    float w = __shfl(pv.w, src);
                    fBP = zero8();
                    if (g == 0) { fBP[0] = (f16)x; fBP[1] = (f16)y; fBP[2] = (f16)zz; fBP[3] = (f16)w; }
                }

                f32x4 aq; aq[0] = bQ0; aq[1] = bQ1; aq[2] = bQ2; aq[3] = bQ3;
                f32x4 ar; ar[0] = bR0; ar[1] = bR1; ar[2] = bR2; ar[3] = bR3;
                f32x4 ag; ag[0] = 0.f; ag[1] = 0.f; ag[2] = 0.f; ag[3] = 0.f;

                uint32_t* Hd = reinterpret_cast<uint32_t*>(Hw);   // dword view, stride 20

#pragma unroll
                for (int X = 0; X < 5; ++X) {
                    const int m0 = 2 * X, m1 = 2 * X + 1;
                    // fA1[m0] from LDS payload
                    {
                        const float* bs = (m0 < 4) ? (bq1 + m0 * 16)
                                        : (m0 < 8) ? (br1 + (m0 - 4) * 16)
                                                   : (bg1 + (m0 - 8) * 16);
                        uint32_t p0 = WA1[(m0 * 16 + c) * 2 + 0];
                        uint32_t p1 = WA1[(m0 * 16 + c) * 2 + 1];
                        uint4 t;
                        t.x = (g == 0) ? p0 : 0u;
                        t.y = (g == 0) ? p1 : 0u;
                        t.z = 0u; t.w = 0u;
                        f16x8 A0;
                        __builtin_memcpy(&A0, &t, 16);
                        f32x4 acc;
                        acc[0] = bs[g * 4 + 0]; acc[1] = bs[g * 4 + 1];
                        acc[2] = bs[g * 4 + 2]; acc[3] = bs[g * 4 + 3];
                        acc = MFMA16(A0, fBP, acc);
                        Hd[c * 20 + g * 2 + 0] = pkrelu(acc[0], acc[1]);
                        Hd[c * 20 + g * 2 + 1] = pkrelu(acc[2], acc[3]);
                    }
                    // fA1[m1]
                    {
                        const float* bs = (m1 < 4) ? (bq1 + m1 * 16)
                                        : (m1 < 8) ? (br1 + (m1 - 4) * 16)
                                                   : (bg1 + (m1 - 8) * 16);
                        uint32_t p0 = WA1[(m1 * 16 + c) * 2 + 0];
                        uint32_t p1 = WA1[(m1 * 16 + c) * 2 + 1];
                        uint4 t;
                        t.x = (g == 0) ? p0 : 0u;
                        t.y = (g == 0) ? p1 : 0u;
                        t.z = 0u; t.w = 0u;
                        f16x8 A1;
                        __builtin_memcpy(&A1, &t, 16);
                        f32x4 acc;
                        acc[0] = bs[g * 4 + 0]; acc[1] = bs[g * 4 + 1];
                        acc[2] = bs[g * 4 + 2]; acc[3] = bs[g * 4 + 3];
                        acc = MFMA16(A1, fBP, acc);
                        Hd[c * 20 + 8 + g * 2 + 0] = pkrelu(acc[0], acc[1]);
                        Hd[c * 20 + 8 + g * 2 + 1] = pkrelu(acc[2], acc[3]);
                    }
                    // GEMM2: fb from H slice, fA2 from LDS
                    f16x8 fb = *reinterpret_cast<const f16x8*>(Hw + c * HSTR + g * 8);
                    f16x8 A2;
                    {
                        uint4 t2 = *reinterpret_cast<const uint4*>(&WA2[(X * 64 + l) * 4]);
                        __builtin_memcpy(&A2, &t2, 16);
                    }
                    if (X == 0)      aq = MFMA16(A2, fb, aq);
                    else if (X == 1) aq = MFMA16(A2, fb, aq);
                    else if (X == 2) ar = MFMA16(A2, fb, ar);
                    else if (X == 3) ar = MFMA16(A2, fb, ar);
                    else             ag = MFMA16(A2, fb, ag);
                }

                const int tt = wv * 64 + n * 16 + c;
                const int ps = spos(tt);
#pragma unroll
                for (int i = 0; i < 4; ++i) {
                    float Qv = softplus_f(aq[i]) + 1e-8f;
                    float Rv = softplus_f(ar[i]) + 1e-8f;
                    auto pk = __builtin_amdgcn_cvt_pkrtz(Qv, Rv);
                    uint32_t w; __builtin_memcpy(&w, &pk, 4);
                    QRl[(size_t)(g * 4 + i) * QSTR + ps] = w;
                }
                if (g == 0)
                    Gl[ps] = sigmoid_f(ag[0] + bG);
            }

            const float4* zq = reinterpret_cast<const float4*>(zb + (size_t)q * QT * KS);
#pragma unroll
            for (int v = 0; v < 4; ++v) {
                int k = tid + 512 * v;
                float4 w = zq[k];
                int t = k >> 2, s0 = (k & 3) << 2;
                const int ps = spos(t);
                zsh[(s0 + 0) * QSTR + ps] = f2h(w.x);
                zsh[(s0 + 1) * QSTR + ps] = f2h(w.y);
                zsh[(s0 + 2) * QSTR + ps] = f2h(w.z);
                zsh[(s0 + 3) * QSTR + ps] = f2h(w.w);
            }
        }
        __syncthreads();

        scan_s(wv, muA, PA);
        scan_s(wv + 8, muB, PB);
        __syncthreads();

        {
            float* od = ob + (size_t)q * QT * KS;
#pragma unroll
            for (int v = 0; v < 4; ++v) {
                int k = tid + 512 * v;
                int t = k >> 2, s0 = (k & 3) << 2;
                const int ps = spos(t);
                float4 w;
                w.x = h2f(zsh[(s0 + 0) * QSTR + ps]);
                w.y = h2f(zsh[(s0 + 1) * QSTR + ps]);
                w.z = h2f(zsh[(s0 + 2) * QSTR + ps]);
                w.w = h2f(zsh[(s0 + 3) * QSTR + ps]);
                *reinterpret_cast<float4*>(od + 4 * (size_t)k) = w;
            }
        }
        __syncthreads();
    }
}

// =====================================================================
// kernel B: fallback — exact R20-proven kernel (weights in registers)
// =====================================================================
__global__ __launch_bounds__(512, 2) void kalman_one(
    const float* __restrict__ z, const float* __restrict__ p,
    const float* __restrict__ mu0, const float* __restrict__ P0,
    const float* __restrict__ Wq1, const float* __restrict__ bq1,
    const float* __restrict__ Wq2, const float* __restrict__ bq2,
    const float* __restrict__ Wr1, const float* __restrict__ br1,
    const float* __restrict__ Wr2, const float* __restrict__ br2,
    const float* __restrict__ Wg1, const float* __restrict__ bg1,
    const float* __restrict__ Wg2, const float* __restrict__ bg2,
    float* __restrict__ out)
{
    __shared__ __align__(16) uint32_t QRl[KS * QSTR];
    __shared__ __align__(16) float    Gl[QT];
    __shared__ __align__(16) uint16_t Hs[8 * KS * HSTR];
    __shared__ __align__(16) uint16_t zsh[KS * QSTR];

    const int tid = threadIdx.x;
    const int wv = tid >> 6;
    const int l = tid & 63;
    const int g = l >> 4;
    const int c = l & 15;
    const int b = blockIdx.x;

    f16* __restrict__ Hw = reinterpret_cast<f16*>(Hs) + wv * (KS * HSTR);

    const float* __restrict__ zb = z + (size_t)b * KT * KS;
    const float* __restrict__ pb = p + (size_t)b * KT * KPD;
    float* __restrict__ ob = out + (size_t)b * KT * KS;

    f16x8 fA1[10];
#pragma unroll
    for (int m = 0; m < 10; ++m) {
        const float* W = (m < 4) ? (Wq1 + m * 16)
                       : (m < 8) ? (Wr1 + (m - 4) * 16)
                                 : (Wg1 + (m - 8) * 16);
        const int ld = (m < 8) ? 64 : 32;
        float w0 = W[0 * ld + c], w1 = W[1 * ld + c],
              w2 = W[2 * ld + c], w3 = W[3 * ld + c];
        f16x8 a = zero8();
        if (g == 0) { a[0] = (f16)w0; a[1] = (f16)w1; a[2] = (f16)w2; a[3] = (f16)w3; }
        fA1[m] = a;
    }
    f16x8 fA2[5];
#pragma unroll
    for (int i = 0; i < 4; ++i) {
        const float* W = (i < 2) ? Wq2 : Wr2;
        const int kb = (i & 1) * 32;
        f16x8 a;
#pragma unroll
        for (int j = 0; j < 8; ++j) a[j] = (f16)W[(kb + g * 8 + j) * 16 + c];
        fA2[i] = a;
    }
    {
        f16x8 a = zero8();
        if (c == 0) {
#pragma unroll
            for (int j = 0; j < 8; ++j) a[j] = (f16)Wg2[g * 8 + j];
        }
        fA2[4] = a;
    }
    const float bQ0 = bq2[g * 4 + 0], bQ1 = bq2[g * 4 + 1],
                bQ2 = bq2[g * 4 + 2], bQ3 = bq2[g * 4 + 3];
    const float bR0 = br2[g * 4 + 0], bR1 = br2[g * 4 + 1],
                bR2 = br2[g * 4 + 2], bR3 = br2[g * 4 + 3];
    const float bG = bg2[0];

    float muA = mu0[b * KS + wv],     PA = P0[b * KS + wv];
    float muB = mu0[b * KS + wv + 8], PB = P0[b * KS + wv + 8];

    auto scan_s = [&](int s, float& mu_q, float& P_q) {
        uint32_t qr[8];
        const uint32_t* qrow = QRl + (size_t)s * QSTR;
        float zvv[8], gvv[8];
#pragma unroll
        for (int i = 0; i < 8; ++i) {
            const int ps = spos(l * 8 + i);
            qr[i] = qrow[ps];
            zvv[i] = h2f(zsh[s * QSTR + ps]);
            gvv[i] = Gl[ps];
        }
        float c00 = 1.f, c01 = 0.f, c10 = 0.f, c11 = 1.f;
#pragma unroll
        for (int i = 0; i < 8; ++i) {
            float Q = h2f_lo(qr[i]), Rr = h2f_hi(qr[i]);
            float ta = fmaf(Q, c10, c00);
            float tb = fmaf(Q, c11, c01);
            float n10 = fmaf(Q + Rr, c10, c00);
            float n11 = fmaf(Q + Rr, c11, c01);
            c00 = Rr * ta; c01 = Rr * tb; c10 = n10; c11 = n11;
        }
        float rn = __builtin_amdgcn_rcpf(c11);
        float ma = c00 * rn, mb = c01 * rn, mc = c10 * rn;
#pragma unroll
        for (int r = 0; r < 6; ++r) {
            const int d = 1 << r;
            float pa = __shfl_up(ma, d);
            float pbv = __shfl_up(mb, d);
            float pc = __shfl_up(mc, d);
            float na = fmaf(ma, pa, mb * pc);
            float nb = fmaf(ma, pbv, mb);
            float nc = fmaf(mc, pa, pc);
            float nd = fmaf(mc, pbv, 1.f);
            float rr = __builtin_amdgcn_rcpf(nd);
            bool act = (l >= d);
            ma = act ? na * rr : ma;
            mb = act ? nb * rr : mb;
            mc = act ? nc * rr : mc;
        }
        float ea = __shfl_up(ma, 1);
        float eb = __shfl_up(mb, 1);
        float ec = __shfl_up(mc, 1);
        if (l == 0) { ea = 1.f; eb = 0.f; ec = 0.f; }
        float P = fmaf(ea, P_q, eb) * __builtin_amdgcn_rcpf(fmaf(ec, P_q, 1.f));

        float av[8], bw[8];
        float A = 1.f, Bv = 0.f;
#pragma unroll
        for (int i = 0; i < 8; ++i) {
            float Q = h2f_lo(qr[i]), Rr = h2f_hi(qr[i]);
            float Pp = P + Q;
            float K0 = Pp * __builtin_amdgcn_rcpf(Pp + Rr);
            float Kk = __builtin_amdgcn_fmed3f(K0, 1e-6f, 0.95f);
            float gk = gvv[i] * Kk;
            av[i] = 1.f - gk;
            bw[i] = gk * zvv[i];
            P = fmaf(-Kk, Pp, Pp);
            A = A * av[i];
            Bv = fmaf(av[i], Bv, bw[i]);
        }
        float P_end = __shfl(P, 63);
#pragma unroll
        for (int r = 0; r < 6; ++r) {
            const int d = 1 << r;
            float pA = __shfl_up(A, d);
            float pB = __shfl_up(Bv, d);
            float nA = A * pA;
            float nB = fmaf(A, pB, Bv);
            bool act = (l >= d);
            A  = act ? nA : A;
            Bv = act ? nB : Bv;
        }
        float eA = __shfl_up(A, 1);
        float eB = __shfl_up(Bv, 1);
        if (l == 0) { eA = 1.f; eB = 0.f; }
        float mu = fmaf(eA, mu_q, eB);
#pragma unroll
        for (int i = 0; i < 8; ++i) {
            mu = fmaf(av[i], mu, bw[i]);
            zsh[s * QSTR + spos(l * 8 + i)] = f2h(mu);
        }
        mu_q = __shfl(mu, 63);
        P_q = P_end;
    };

    for (int q = 0; q < NQ; ++q) {
        {
            const int trow = q * QT + wv * 64;
            const float4 pv = *reinterpret_cast<const float4*>(pb + (size_t)(trow + l) * KPD);

#pragma unroll
            for (int n = 0; n < 4; ++n) {
                f16x8 fBP;
                {
                    const int src = n * 16 + c;
                    float x = __shfl(pv.x, src);
                    float y = __shfl(pv.y, src);
                    float zz = __shfl(pv.z, src);
                    float w = __shfl(pv.w, src);
                    fBP = zero8();
                    if (g == 0) { fBP[0] = (f16)x; fBP[1] = (f16)y; fBP[2] = (f16)zz; fBP[3] = (f16)w; }
                }

                f32x4 aq; aq[0] = bQ0; aq[1] = bQ1; aq[2] = bQ2; aq[3] = bQ3;
                f32x4 ar; ar[0] = bR0; ar[1] = bR1; ar[2] = bR2; ar[3] = bR3;
                f32x4 ag; ag[0] = 0.f; ag[1] = 0.f; ag[2] = 0.f; ag[3] = 0.f;

                uint32_t* Hd = reinterpret_cast<uint32_t*>(Hw);

#pragma unroll
                for (int X = 0; X < 5; ++X) {
                    const int m0 = 2 * X, m1 = 2 * X + 1;
                    {
                        const float* bs = (m0 < 4) ? (bq1 + m0 * 16)
                                        : (m0 < 8) ? (br1 + (m0 - 4) * 16)
                                                   : (bg1 + (m0 - 8) * 16);
                        f32x4 acc;
                        acc[0] = bs[g * 4 + 0]; acc[1] = bs[g * 4 + 1];
                        acc[2] = bs[g * 4 + 2]; acc[3] = bs[g * 4 + 3];
                        acc = MFMA16(fA1[m0], fBP, acc);
                        Hd[c * 20 + g * 2 + 0] = pkrelu(acc[0], acc[1]);
                        Hd[c * 20 + g * 2 + 1] = pkrelu(acc[2], acc[3]);
                    }
                    {
                        const float* bs = (m1 < 4) ? (bq1 + m1 * 16)
                                        : (m1 < 8) ? (br1 + (m1 - 4) * 16)
                                                   : (bg1 + (m1 - 8) * 16);
                        f32x4 acc;
                        acc[0] = bs[g * 4 + 0]; acc[1] = bs[g * 4 + 1];
                        acc[2] = bs[g * 4 + 2]; acc[3] = bs[g * 4 + 3];
                        acc = MFMA16(fA1[m1], fBP, acc);
                        Hd[c * 20 + 8 + g * 2 + 0] = pkrelu(acc[0], acc[1]);
                        Hd[c * 20 + 8 + g * 2 + 1] = pkrelu(acc[2], acc[3]);
                    }
                    f16x8 fb = *reinterpret_cast<const f16x8*>(Hw + c * HSTR + g * 8);
                    if (X == 0)      aq = MFMA16(fA2[0], fb, aq);
                    else if (X == 1) aq = MFMA16(fA2[1], fb, aq);
                    else if (X == 2) ar = MFMA16(fA2[2], fb, ar);
                    else if (X == 3) ar = MFMA16(fA2[3], fb, ar);
                    else             ag = MFMA16(fA2[4], fb, ag);
                }

                const int tt = wv * 64 + n * 16 + c;
                const int ps = spos(tt);
#pragma unroll
                for (int i = 0; i < 4; ++i) {
                    float Qv = softplus_f(aq[i]) + 1e-8f;
                    float Rv = softplus_f(ar[i]) + 1e-8f;
                    auto pk = __builtin_amdgcn_cvt_pkrtz(Qv, Rv);
                    uint32_t w; __builtin_memcpy(&w, &pk, 4);
                    QRl[(size_t)(g * 4 + i) * QSTR + ps] = w;
                }
                if (g == 0)
                    Gl[ps] = sigmoid_f(ag[0] + bG);
            }

            const float4* zq = reinterpret_cast<const float4*>(zb + (size_t)q * QT * KS);
#pragma unroll
            for (int v = 0; v < 4; ++v) {
                int k = tid + 512 * v;
                float4 w = zq[k];
                int t = k >> 2, s0 = (k & 3) << 2;
                const int ps = spos(t);
                zsh[(s0 + 0) * QSTR + ps] = f2h(w.x);
                zsh[(s0 + 1) * QSTR + ps] = f2h(w.y);
                zsh[(s0 + 2) * QSTR + ps] = f2h(w.z);
                zsh[(s0 + 3) * QSTR + ps] = f2h(w.w);
            }
        }
        __syncthreads();

        scan_s(wv, muA, PA);
        scan_s(wv + 8, muB, PB);
        __syncthreads();

        {
            float* od = ob + (size_t)q * QT * KS;
#pragma unroll
            for (int v = 0; v < 4; ++v) {
                int k = tid + 512 * v;
                int t = k >> 2, s0 = (k & 3) << 2;
                const int ps = spos(t);
                float4 w;
                w.x = h2f(zsh[(s0 + 0) * QSTR + ps]);
                w.y = h2f(zsh[(s0 + 1) * QSTR + ps]);
                w.z = h2f(zsh[(s0 + 2) * QSTR + ps]);
                w.w = h2f(zsh[(s0 + 3) * QSTR + ps]);
                *reinterpret_cast<float4*>(od + 4 * (size_t)k) = w;
            }
        }
        __syncthreads();
    }
}

// ---------------- launcher ----------------
extern "C" void kernel_launch(void* const* d_in, const int* in_sizes, int n_in,
                              void* d_out, int out_size, void* d_ws, size_t ws_size,
                              hipStream_t stream) {
    const float* z   = (const float*)d_in[0];
    const float* p   = (const float*)d_in[1];
    const float* mu0 = (const float*)d_in[2];
    const float* P0  = (const float*)d_in[3];
    const float* Wq1 = (const float*)d_in[4];
    const float* bq1 = (const float*)d_in[5];
    const float* Wq2 = (const float*)d_in[6];
    const float* bq2 = (const float*)d_in[7];
    const float* Wr1 = (const float*)d_in[8];
    const float* br1 = (const float*)d_in[9];
    const float* Wr2 = (const float*)d_in[10];
    const float* br2 = (const float*)d_in[11];
    const float* Wg1 = (const float*)d_in[12];
    const float* bg1 = (const float*)d_in[13];
    const float* Wg2 = (const float*)d_in[14];
    const float* bg2 = (const float*)d_in[15];
    float* out = (float*)d_out;

    // Spill signature = scratch bytes per thread (localSizeBytes), NOT numRegs
    // (R21 lesson: numRegs includes AGPRs and mis-detects).
    hipFuncAttributes attr{};
    bool use_fast = false;
    if (hipFuncGetAttributes(&attr, (const void*)kalman_fast) == hipSuccess)
        use_fast = (attr.localSizeBytes <= 16);

    if (use_fast) {
        hipLaunchKernelGGL(kalman_fast, dim3(KB), dim3(512), 0, stream,
                           z, p, mu0, P0, Wq1, bq1, Wq2, bq2,
                           Wr1, br1, Wr2, br2, Wg1, bg1, Wg2, bg2, out);
    } else {
        hipLaunchKernelGGL(kalman_one, dim3(KB), dim3(512), 0, stream,
                           z, p, mu0, P0, Wq1, bq1, Wq2, bq2,
                           Wr1, br1, Wr2, br2, Wg1, bg1, Wg2, bg2, out);
    }
}